// Round 5
// baseline (307.224 us; speedup 1.0000x reference)
//
#include <hip/hip_runtime.h>
#include <math.h>

#define NEGINF (-INFINITY)
#define NEGINF_BITS ((int)0xFF800000)

typedef unsigned int u32;
typedef unsigned long long u64;

#define RST 128  // rows staged in LDS (128 KiB dynamic shared)

__device__ __forceinline__ int rl_i(int x, int l) {
    return __builtin_amdgcn_readlane(x, l);
}
__device__ __forceinline__ float rl_f(float x, int l) {
    return __int_as_float(__builtin_amdgcn_readlane(__float_as_int(x), l));
}

// Joint top-2 wave reduction over a SINGLE ROW's 256 values (rescan path),
// given lane-local top-2 (lv,lf) >= (lv2,lf2), first-occurrence ordering.
// One 6-stage DPP chain carries (top, second); DPP old = NEGINF injects the
// neutral element for invalid source lanes. (Verified R3/R4, absmax=0.)
__device__ __forceinline__ void wave_top2(float lv, int lf, float lv2, int lf2,
                                          float& nv, int& nc, float& nv2, int& nc2) {
    float av = lv, bv = lv2;
#define T2STAGE(CTRL) {                                                        \
        float a2 = __int_as_float(__builtin_amdgcn_update_dpp(                 \
            NEGINF_BITS, __float_as_int(av), CTRL, 0xf, 0xf, false));          \
        float b2 = __int_as_float(__builtin_amdgcn_update_dpp(                 \
            NEGINF_BITS, __float_as_int(bv), CTRL, 0xf, 0xf, false));          \
        float t = fminf(av, a2);                                               \
        av = fmaxf(av, a2);                                                    \
        bv = fmaxf(fmaxf(bv, b2), t); }
    T2STAGE(0x111) T2STAGE(0x112) T2STAGE(0x114) T2STAGE(0x118)
    T2STAGE(0x142) T2STAGE(0x143)
#undef T2STAGE
    nv = rl_f(av, 63);
    float sv = rl_f(bv, 63);

    u64 m1 = __ballot(lv == nv);
    int ln = (int)__builtin_ctzll(m1);
    nc = rl_i(lf, ln);

    nv2 = sv; nc2 = 300;
    if (sv > 0.f) {
        if (sv == nv) {
            // duplicate max: candidates are lane ln's lf2 (if lv2==nv) or the
            // next lane in m1 (lowest-col-first within/across lanes).
            float b2v = rl_f(lv2, ln);
            if (b2v == nv) {
                nc2 = rl_i(lf2, ln);
            } else {
                u64 rest = m1 & (m1 - 1);
                int l2 = (int)__builtin_ctzll(rest);
                nc2 = rl_i(lf, l2);
            }
        } else {
            u64 m2 = __ballot(lv == sv || lv2 == sv);
            int l2 = (int)__builtin_ctzll(m2);
            float tl = rl_f(lv, l2);
            nc2 = (tl == sv) ? rl_i(lf, l2) : rl_i(lf2, l2);
        }
    }
}

// Joint top-2 wave reduction over the 256 cached ROW-BESTS (main argmax).
// flat = row<<8 | col; ordering (value desc, flat asc), matching jnp.argmax
// first-occurrence over the flattened scores. Per-lane input: top (lv,lf),
// second (lv2,lf2) over the lane's 4 rows (flat-asc within equal values).
// Outputs: global top (nv,nf) and second (sv,sf). Distinct rows guaranteed
// (each row contributes one candidate). sf valid only when sv > 0.
__device__ __forceinline__ void wave_top2_flat(float lv, int lf, float lv2, int lf2,
                                               float& nv, int& nf, float& sv, int& sf) {
    float av = lv, bv = lv2;
#define T2STAGE(CTRL) {                                                        \
        float a2 = __int_as_float(__builtin_amdgcn_update_dpp(                 \
            NEGINF_BITS, __float_as_int(av), CTRL, 0xf, 0xf, false));          \
        float b2 = __int_as_float(__builtin_amdgcn_update_dpp(                 \
            NEGINF_BITS, __float_as_int(bv), CTRL, 0xf, 0xf, false));          \
        float t = fminf(av, a2);                                               \
        av = fmaxf(av, a2);                                                    \
        bv = fmaxf(fmaxf(bv, b2), t); }
    T2STAGE(0x111) T2STAGE(0x112) T2STAGE(0x114) T2STAGE(0x118)
    T2STAGE(0x142) T2STAGE(0x143)
#undef T2STAGE
    nv = rl_f(av, 63);
    sv = rl_f(bv, 63);

    // top flat: lowest flat among lanes holding nv (lanes hold distinct rows,
    // so distinct flats; multi-lane ties are exact-duplicate values: rare).
    u64 m1 = __ballot(lv == nv);
    int ln = (int)__builtin_ctzll(m1);
    nf = rl_i(lf, ln);
    u64 rest = m1 & (m1 - 1);
    if (rest) {                                   // rare exact-tie path
        while (rest) {
            int l2 = (int)__builtin_ctzll(rest); rest &= rest - 1;
            int f = rl_i(lf, l2);
            if (f < nf) nf = f;
        }
    }

    sf = 0x7FFFFFFF;
    if (sv > 0.f) {
        if (sv == nv) {
            // duplicate of the top value (rare): min flat among all
            // value==nv candidates excluding nf itself.
            int best = 0x7FFFFFFF;
            u64 mm = m1;
            while (mm) {
                int l2 = (int)__builtin_ctzll(mm); mm &= mm - 1;
                int f = rl_i(lf, l2);
                if (f != nf && f < best) best = f;
                float v2 = rl_f(lv2, l2);
                if (v2 == nv) {
                    int g = rl_i(lf2, l2);
                    if (g != nf && g < best) best = g;
                }
            }
            sf = best;
        } else {
            u64 m2 = __ballot(lv == sv || lv2 == sv);
            u64 rest2 = m2 & (m2 - 1);
            int l2 = (int)__builtin_ctzll(m2);
            if (!rest2) {                          // fast path: unique holder
                float tl = rl_f(lv, l2);
                sf = (tl == sv) ? rl_i(lf, l2) : rl_i(lf2, l2);
            } else {                               // rare exact-tie path
                int best = 0x7FFFFFFF;
                while (m2) {
                    int l3 = (int)__builtin_ctzll(m2); m2 &= m2 - 1;
                    float tl = rl_f(lv, l3);
                    int f = (tl == sv) ? rl_i(lf, l3) : rl_i(lf2, l3);
                    if (f < best) best = f;
                }
                sf = best;
            }
        }
    }
}

// One wave (64 lanes) per batch. Lane l owns rows {j*64+l : j=0..3}:
//   rv[j]/rc[j]  : row's exact best (value, col) over untaken cols; rc==300 = DEAD.
//   spv[j]/spc[j]: row's exact runner-up (spare), eagerly invalidated when its
//                  col is taken; spc==300 = none.
// Lane l owns taken-bits for cols 4l..4l+3 (colmask).
// DUAL-ASSIGN: the main reduction extracts top-2. Previous-second is exactly
// the next argmax iff second.col != c1 (its row stays clean; rows are distinct
// by construction) and no dirty row's old best ties second's value (ballot
// guard). When it holds (~99%), both are assigned in ONE iteration; dirty
// handling processes both cols at once (colmask updated first, spares for
// both cols invalidated, so advances/rescans exclude both; an advanced
// spare's col is provably outside {c1,c2} -> no cascade).
template <int RSTT>
__global__ __launch_bounds__(64, 1) void greedy_perm_kernel(
        const float* __restrict__ soft, float* __restrict__ out) {
    extern __shared__ float smem[];               // RSTT rows x 256 floats
    const int b = blockIdx.x;
    const int lane = threadIdx.x;
    const size_t base = (size_t)b << 16;          // b * 256 * 256
    const float* sc = soft + base;
    float* ob = out + base;

    float rv[4], spv[4];
    int   rc[4], spc[4];
#pragma unroll
    for (int j = 0; j < 4; ++j) { rv[j] = NEGINF; rc[j] = 0; spv[j] = NEGINF; spc[j] = 300; }

    const float4 zero4 = make_float4(0.f, 0.f, 0.f, 0.f);

    // ---- initial per-row top-2 scan, 16 loads in flight, fused zero-fill of
    // ---- out, fused LDS staging of rows 0..RSTT-1 (chunk-XOR swizzled) ----
    for (int k = 0; k < 64; k += 4) {
        float4 w[4][4];
#pragma unroll
        for (int j = 0; j < 4; ++j) {
            const float4* rp = (const float4*)(sc + (size_t)(j * 64 + lane) * 256);
#pragma unroll
            for (int kk = 0; kk < 4; ++kk) w[j][kk] = rp[k + kk];
        }
#pragma unroll
        for (int j = 0; j < 4; ++j) {
            float4* op = (float4*)(ob + (size_t)(j * 64 + lane) * 256);
#pragma unroll
            for (int kk = 0; kk < 4; ++kk) op[k + kk] = zero4;
        }
        if (RSTT > 0) {
#pragma unroll
            for (int j = 0; j < 2; ++j) {
                float* lp = &smem[(j * 64 + lane) << 8];
#pragma unroll
                for (int kk = 0; kk < 4; ++kk)
                    *(float4*)&lp[((k + kk) ^ lane) << 2] = w[j][kk];
            }
        }
#pragma unroll
        for (int j = 0; j < 4; ++j) {
#pragma unroll
            for (int kk = 0; kk < 4; ++kk) {
                const float4 ww = w[j][kk];
                const int bc = 4 * (k + kk);
                const float e[4] = {ww.x, ww.y, ww.z, ww.w};
#pragma unroll
                for (int q = 0; q < 4; ++q) {
                    const float x = e[q];
                    const int   cx = bc + q;
                    const bool g1 = x > rv[j];
                    const bool g2 = x > spv[j];
                    spv[j] = g1 ? rv[j] : (g2 ? x  : spv[j]);
                    spc[j] = g1 ? rc[j] : (g2 ? cx : spc[j]);
                    rv[j]  = g1 ? x  : rv[j];
                    rc[j]  = g1 ? cx : rc[j];
                }
            }
        }
    }

    // Drain zero-stores before any 1.0 store can target the same address.
    __threadfence_block();

    u32 colmask = 0;   // 4 bits: cols 4*lane..4*lane+3 assigned?

    // ---- greedy steps, up to 2 assignments per iteration ----
    int step = 0;
    while (step < 256) {
        // lane-local top-2 over the 4 owned rows (j-ascending => flat-asc ties)
        float bv = rv[0];
        int   bf = (lane << 8) | (rc[0] & 255);
        float bv2 = NEGINF;
        int   bf2 = bf;
#pragma unroll
        for (int j = 1; j < 4; ++j) {
            const float v = rv[j];
            const int   f = (((j << 6) + lane) << 8) | (rc[j] & 255);
            const bool g1 = v > bv, g2 = v > bv2;
            bv2 = g1 ? bv : (g2 ? v : bv2);
            bf2 = g1 ? bf : (g2 ? f : bf2);
            bv  = g1 ? v : bv;
            bf  = g1 ? f : bf;
        }
        float nv, svv; int gf, f2;
        wave_top2_flat(bv, bf, bv2, bf2, nv, gf, svv, f2);
        const int r1 = gf >> 8;
        const int c1 = gf & 255;

        if (lane == 0) ob[gf] = 1.0f;            // hard[r1][c1] = 1
        if (lane == (r1 & 63)) {                 // winner row -> dead
            const int rj = r1 >> 6;
#pragma unroll
            for (int j = 0; j < 4; ++j) if (j == rj) { rv[j] = NEGINF; rc[j] = 300; }
        }
        if (lane == (c1 >> 2)) colmask |= 1u << (c1 & 3);

        // dirty-on-c1 flags (after r1 kill) + exact-tie guard vs second value
        bool dd1[4]; bool tie = false;
#pragma unroll
        for (int j = 0; j < 4; ++j) {
            dd1[j] = (rc[j] == c1);
            tie |= dd1[j] && (rv[j] == svv);
        }
        const u64 tb = __ballot(tie);
        const bool use2 = (svv > 0.f) && ((f2 & 255) != c1) && (tb == 0ull);

        int c2 = -1;                              // -1: never matches rc/spc
        if (use2) {
            const int r2 = f2 >> 8;
            c2 = f2 & 255;
            if (lane == 0) ob[f2] = 1.0f;        // hard[r2][c2] = 1
            if (lane == (r2 & 63)) {
                const int rj = r2 >> 6;
#pragma unroll
                for (int j = 0; j < 4; ++j) if (j == rj) { rv[j] = NEGINF; rc[j] = 300; }
            }
            if (lane == (c2 >> 2)) colmask |= 1u << (c2 & 3);
        }

        // eager spare invalidation for both taken cols
#pragma unroll
        for (int j = 0; j < 4; ++j)
            if (spc[j] == c1 || spc[j] == c2) spc[j] = 300;

        // dirty rows: live spare -> in-register advance; else mark for rescan.
        u32 needmask = 0;
#pragma unroll
        for (int j = 0; j < 4; ++j) {
            const bool dirty = dd1[j] || (rc[j] == c2);
            const bool have  = (spc[j] < 300);
            if (dirty && have) {                  // exact advance, no memory
                rv[j] = spv[j]; rc[j] = spc[j];
                spv[j] = NEGINF; spc[j] = 300;
            }
            if (dirty && !have) needmask |= 1u << j;
        }

        u64 nb = __ballot(needmask != 0);
        while (nb) {                              // usually empty
            const int l = (int)__builtin_ctzll(nb); nb &= nb - 1;
            u32 nm = (u32)rl_i((int)needmask, l);
            while (nm) {
                const int j = (int)__builtin_ctzll(nm); nm &= nm - 1;
                const int row = (j << 6) + l;
                // coalesced: 64 lanes x float4 = the whole 256-float row
                float4 w = (RSTT > 0 && row < RSTT)
                    ? *(const float4*)&smem[(row << 8) | (((lane ^ l) & 63) << 2)]
                    : *(const float4*)(sc + ((size_t)row << 8) + (lane << 2));
                const float q0 = (colmask & 1u) ? NEGINF : w.x;
                const float q1 = (colmask & 2u) ? NEGINF : w.y;
                const float q2 = (colmask & 4u) ? NEGINF : w.z;
                const float q3 = (colmask & 8u) ? NEGINF : w.w;
                const int cb = lane << 2;
                float lv = q0; int lf = cb;
                float lv2 = NEGINF; int lf2 = cb;
                {
                    bool g1 = q1 > lv, g2 = q1 > lv2;
                    lv2 = g1 ? lv : (g2 ? q1 : lv2); lf2 = g1 ? lf : (g2 ? cb + 1 : lf2);
                    lv  = g1 ? q1 : lv;              lf  = g1 ? cb + 1 : lf;
                    g1 = q2 > lv; g2 = q2 > lv2;
                    lv2 = g1 ? lv : (g2 ? q2 : lv2); lf2 = g1 ? lf : (g2 ? cb + 2 : lf2);
                    lv  = g1 ? q2 : lv;              lf  = g1 ? cb + 2 : lf;
                    g1 = q3 > lv; g2 = q3 > lv2;
                    lv2 = g1 ? lv : (g2 ? q3 : lv2); lf2 = g1 ? lf : (g2 ? cb + 3 : lf2);
                    lv  = g1 ? q3 : lv;              lf  = g1 ? cb + 3 : lf;
                }
                float fv, fv2; int fc, fc2;
                wave_top2(lv, lf, lv2, lf2, fv, fc, fv2, fc2);
                if (lane == l) {
#pragma unroll
                    for (int jj = 0; jj < 4; ++jj) if (jj == j) {
                        rv[jj] = fv; rc[jj] = fc;
                        spv[jj] = fv2; spc[jj] = fc2;   // fc2==300 if none
                    }
                }
            }
        }

        step += use2 ? 2 : 1;
    }
}

extern "C" void kernel_launch(void* const* d_in, const int* in_sizes, int n_in,
                              void* d_out, int out_size, void* d_ws, size_t ws_size,
                              hipStream_t stream) {
    const float* soft = (const float*)d_in[0];
    float* out = (float*)d_out;
    const int n_batches = in_sizes[0] >> 16;   // elements / (256*256)

    // 128 KiB dynamic LDS needs the attribute raised once; fall back to the
    // no-staging instantiation if the runtime refuses.
    static int use_lds = -1;
    if (use_lds < 0) {
        hipError_t e = hipFuncSetAttribute(
            reinterpret_cast<const void*>(greedy_perm_kernel<RST>),
            hipFuncAttributeMaxDynamicSharedMemorySize, RST * 256 * 4);
        use_lds = (e == hipSuccess) ? 1 : 0;
    }
    if (use_lds)
        greedy_perm_kernel<RST><<<n_batches, 64, RST * 256 * 4, stream>>>(soft, out);
    else
        greedy_perm_kernel<0><<<n_batches, 64, 0, stream>>>(soft, out);
}